// Round 7
// baseline (14225.795 us; speedup 1.0000x reference)
//
#include <hip/hip_runtime.h>
#include <math.h>

#define SEQ    1024
#define EMBED  300
#define HIDDEN 512
#define G4     2048          // 4*HIDDEN, gate order i,f,g,o
#define NB     32            // worker blocks in phase 2
#define NBLK   256           // total blocks (32 workers + 224 heaters)
#define TPB    1024          // threads per block (16 waves)
#define UPB    (HIDDEN/NB)   // hidden units owned per worker block = 16
#define PAD_IDX 1
#define SENT   0x7FC00BADu   // NaN bit pattern: never produced by LSTM math

// g_hp layout: [step][worker][32 floats] -- 128 B per producer per step:
// each producer owns its cache line exclusively.
#define HSLOT  32
#define HROW   (NB * HSLOT)   // 1024 floats per step

// s_getreg encoding: id | offset<<6 | (size-1)<<11 ; HW_REG_XCC_ID = 20
#define HWREG_XCC_ID (20 | (0 << 6) | ((4 - 1) << 11))

// ---- device-global scratch. Fully re-initialized by phase 1 every call. ----
__device__ float        g_xg[SEQ * G4];            // x @ W_ih^T + b_ih + b_hh
__device__ float        g_hp[(SEQ + 1) * HROW];    // padded per-step h buffers
__device__ unsigned int g_done;                    // heater kill switch
__device__ unsigned int g_cnt[8];                  // per-XCD ticket counters
__device__ unsigned int g_arr;                     // arrival counter
__device__ float        g_sink;                    // keeps heater loops alive

__device__ __forceinline__ float sigmoidf_(float x) {
    return 1.f / (1.f + __expf(-x));
}
// saturating fast tanh: 1 - 2/(e^2x + 1)
__device__ __forceinline__ float tanhf_(float x) {
    return 1.f - 2.f / (__expf(2.f * x) + 1.f);
}

// DPP butterfly add over 16-lane rows (xor 1,2,7,15)
#define DPP_ADD(v, ctrl)                                                      \
    (v) += __int_as_float(__builtin_amdgcn_update_dpp(                        \
        0, __float_as_int(v), (ctrl), 0xf, 0xf, true))

// ---------------------------------------------------------------------------
// Phase 1: xg[t][k] = dot(emb[token[t]], W_ih[k]) + b_ih[k] + b_hh[k]
// grid = 256 blocks (128 t-tiles of 8 tokens x 2 k-halves), 256 threads.
// Also: g_hp step 0 = h0, steps 1..SEQ = sentinel; control vars zeroed.
// ---------------------------------------------------------------------------
__global__ __launch_bounds__(256) void xgates_kernel(
    const int* __restrict__ seq, const float* __restrict__ h0,
    const float* __restrict__ emb, const float* __restrict__ W_ih,
    const float* __restrict__ b_ih, const float* __restrict__ b_hh)
{
    const int bx = blockIdx.x, tid = threadIdx.x;

    if (bx == 0 && tid == 0) {
        g_done = 0u;
        g_arr  = 0u;
        for (int x = 0; x < 8; x++) g_cnt[x] = 0u;
    }
    for (int i = bx * 256 + tid; i < (SEQ + 1) * HROW; i += 256 * 256) {
        int step = i >> 10, slot = i & (HROW - 1);
        int blk = slot >> 5, k = slot & (HSLOT - 1);
        float v = __uint_as_float(SENT);
        if (step == 0 && k < UPB) v = h0[blk * UPB + k];
        g_hp[i] = v;
    }

    const int t_tile = bx >> 1, k_half = bx & 1;
    const int t0 = t_tile * 8;

    __shared__ int tok_s[8];
    __shared__ __align__(16) float embt[8][304];

    if (tid < 8) tok_s[tid] = seq[t0 + tid];
    __syncthreads();
    for (int idx = tid; idx < 8 * EMBED; idx += 256) {
        int tt = idx / EMBED;
        int e  = idx - tt * EMBED;
        embt[tt][e] = emb[(size_t)tok_s[tt] * EMBED + e];
    }
    __syncthreads();

    const int kbase = k_half * 1024 + tid;
    const float4* wr0 = (const float4*)(W_ih + (size_t)(kbase      ) * EMBED);
    const float4* wr1 = (const float4*)(W_ih + (size_t)(kbase + 256) * EMBED);
    const float4* wr2 = (const float4*)(W_ih + (size_t)(kbase + 512) * EMBED);
    const float4* wr3 = (const float4*)(W_ih + (size_t)(kbase + 768) * EMBED);

    float acc[4][8];
    #pragma unroll
    for (int kk = 0; kk < 4; kk++)
        #pragma unroll
        for (int tt = 0; tt < 8; tt++) acc[kk][tt] = 0.f;

    for (int e4 = 0; e4 < EMBED / 4; e4++) {  // 75 iters
        float4 em[8];
        #pragma unroll
        for (int tt = 0; tt < 8; tt++)
            em[tt] = *(const float4*)&embt[tt][e4 * 4];
        float4 w[4];
        w[0] = wr0[e4]; w[1] = wr1[e4]; w[2] = wr2[e4]; w[3] = wr3[e4];
        #pragma unroll
        for (int kk = 0; kk < 4; kk++) {
            #pragma unroll
            for (int tt = 0; tt < 8; tt++) {
                float a = acc[kk][tt];
                a = fmaf(w[kk].x, em[tt].x, a);
                a = fmaf(w[kk].y, em[tt].y, a);
                a = fmaf(w[kk].z, em[tt].z, a);
                a = fmaf(w[kk].w, em[tt].w, a);
                acc[kk][tt] = a;
            }
        }
    }
    #pragma unroll
    for (int kk = 0; kk < 4; kk++) {
        int k = kbase + kk * 256;
        float bias = b_ih[k] + b_hh[k];
        #pragma unroll
        for (int tt = 0; tt < 8; tt++)
            g_xg[(size_t)(t0 + tt) * G4 + k] = acc[kk][tt] + bias;
    }
}

// ---------------------------------------------------------------------------
// Phase 2: persistent cooperative LSTM, workers COLOCATED ON ONE XCD so the
// per-step h exchange rides the XCD-local coherent L2 (~200 cy) instead of
// the MALL (~600 cy, the R2-R6 invariant floor).
//
// Role assignment (scheduling-independent): every block reads its physical
// XCD (s_getreg XCC_ID), takes a per-XCD ticket, syncs once on an arrival
// counter (all 256 co-resident by cooperative launch), then all blocks pick
// the first XCD with >=32 resident blocks (pigeonhole guarantees one).
// That XCD's first 32 ticket-holders = workers (id = ticket); rest = FMA
// heaters (R5: +44% from keeping SCLK boosted).
//
// h exchange: producers dual-publish (sc0 store -> XCD L2, agent store ->
// MALL); pollers use SE-scope sc0 loads (bypass L1, hit shared L2), with
// an agent-scope fallback after 64 tries -- degraded-mode-safe even if
// XCC_ID misreads or workers split across XCDs (no hang possible).
// ---------------------------------------------------------------------------
__global__ __launch_bounds__(TPB, 1) void lstm_kernel(
    const int* __restrict__ seq, const float* __restrict__ h0,
    const float* __restrict__ c0, const float* __restrict__ Whh,
    float* __restrict__ out)
{
    const int tid = threadIdx.x;

    __shared__ unsigned s_role;
    if (tid == 0) {
        unsigned xcc = (unsigned)__builtin_amdgcn_s_getreg(HWREG_XCC_ID) & 7u;
        unsigned idx = __hip_atomic_fetch_add(&g_cnt[xcc], 1u,
                           __ATOMIC_RELAXED, __HIP_MEMORY_SCOPE_AGENT);
        __hip_atomic_fetch_add(&g_arr, 1u,
                           __ATOMIC_ACQ_REL, __HIP_MEMORY_SCOPE_AGENT);
        while (__hip_atomic_load(&g_arr, __ATOMIC_ACQUIRE,
                                 __HIP_MEMORY_SCOPE_AGENT) < NBLK)
            __builtin_amdgcn_s_sleep(2);
        unsigned target = 0u;
        for (int x = 0; x < 8; x++) {
            if (__hip_atomic_load(&g_cnt[x], __ATOMIC_RELAXED,
                                  __HIP_MEMORY_SCOPE_AGENT) >= NB) {
                target = (unsigned)x; break;
            }
        }
        s_role = (xcc == target && idx < NB) ? idx : 0xFFFFFFFFu;
    }
    __syncthreads();
    const unsigned role = s_role;

    if (role == 0xFFFFFFFFu) {
        // ---------------- heater ----------------
        if (tid < 256) {
            float a0 = 1.0f + tid, a1 = 2.0f, a2 = 3.0f, a3 = 4.0f;
            for (;;) {
                #pragma unroll
                for (int i = 0; i < 128; i++) {
                    a0 = fmaf(a0, 1.000001f, 0.5f);
                    a1 = fmaf(a1, 0.999999f, 0.25f);
                    a2 = fmaf(a2, 1.0000005f, a0);
                    a3 = fmaf(a3, 0.9999995f, a1);
                }
                if (__hip_atomic_load(&g_done, __ATOMIC_RELAXED,
                                      __HIP_MEMORY_SCOPE_AGENT)) break;
            }
            if (a0 == 1234.5678f && a1 == a2) g_sink = a3;
        }
        return;
    }

    // ---------------- worker ----------------
    const int b = (int)role;
    const int u = tid >> 6;            // wave id = owned unit 0..15
    const int lane = tid & 63;
    const int c = lane & 15;
    const int g = lane >> 4;
    const int R = g * HIDDEN + b * UPB + u;    // W_hh row

    const float* wrow = Whh + (size_t)R * HIDDEN + c * 32;
    float4 wreg[8];
    #pragma unroll
    for (int i = 0; i < 8; i++) {
        int off = (4 * i + 4 * c) & 31;   // rotated traversal
        wreg[i] = *(const float4*)(wrow + off);
    }

    __shared__ __align__(16) float h_lds[2][HIDDEN];
    __shared__ int tok_lds[SEQ];

    for (int i = tid; i < SEQ; i += TPB) tok_lds[i] = seq[i];

    const bool owner = (lane == 0);
    float c_state = 0.f, h_state = 0.f;
    if (owner) {
        c_state = c0[b * UPB + u];
        h_state = h0[b * UPB + u];
    }
    __syncthreads();   // tok_lds ready

    int np = 0;
    bool any = false;

    for (int t = 0; t < SEQ; t++) {
        int tok = tok_lds[t];             // uniform LDS read
        if (tok == PAD_IDX) continue;     // uniform across grid
        any = true;

        // threads 0..255: ONE 8-B poll each; value is its own ready flag.
        if (tid < 256) {
            const int blk = tid >> 3, j = tid & 7;
            const unsigned long long* hb = (const unsigned long long*)
                (g_hp + (size_t)np * HROW + blk * HSLOT) + j;
            unsigned long long v;
            int tries = 64;
            for (;;) {
                // SE-scope load: bypass L1, served by the shared XCD L2
                asm volatile("global_load_dwordx2 %0, %1, off sc0\n\t"
                             "s_waitcnt vmcnt(0)"
                             : "=v"(v) : "v"(hb) : "memory");
                if ((unsigned)v != SENT && (unsigned)(v >> 32) != SENT) break;
                if (--tries == 0) {       // degraded mode: MALL path
                    do {
                        v = __hip_atomic_load(hb, __ATOMIC_RELAXED,
                                              __HIP_MEMORY_SCOPE_AGENT);
                    } while ((unsigned)v == SENT || (unsigned)(v >> 32) == SENT);
                    break;
                }
            }
            *(unsigned long long*)&h_lds[np & 1][blk * UPB + 2 * j] = v;
        }
        __syncthreads();   // the only barrier per step

        // owner xg loads issued here; latency hides under the dot (vmcnt)
        float xi = 0.f, xf = 0.f, xgg = 0.f, xo = 0.f;
        if (owner) {
            const float* xr = g_xg + (size_t)t * G4 + b * UPB + u;
            xi  = xr[0];
            xf  = xr[HIDDEN];
            xgg = xr[2 * HIDDEN];
            xo  = xr[3 * HIDDEN];
        }

        // 32-length partial dot: W from VGPRs, h via LDS broadcasts
        const float* hc = h_lds[np & 1] + c * 32;
        float4 a4 = {0.f, 0.f, 0.f, 0.f};
        #pragma unroll
        for (int i = 0; i < 8; i++) {
            int off = (4 * i + 4 * c) & 31;
            float4 h4 = *(const float4*)(hc + off);
            a4.x = fmaf(wreg[i].x, h4.x, a4.x);
            a4.y = fmaf(wreg[i].y, h4.y, a4.y);
            a4.z = fmaf(wreg[i].z, h4.z, a4.z);
            a4.w = fmaf(wreg[i].w, h4.w, a4.w);
        }
        float dotv = (a4.x + a4.y) + (a4.z + a4.w);
        // 16-lane butterfly via DPP (xor1, xor2, xor7, xor15): pure VALU
        DPP_ADD(dotv, 0xB1);    // quad_perm [1,0,3,2]
        DPP_ADD(dotv, 0x4E);    // quad_perm [2,3,0,1]
        DPP_ADD(dotv, 0x141);   // row_half_mirror
        DPP_ADD(dotv, 0x140);   // row_mirror

        // owner (lane 0) holds d0; gather d1..d3 (3 parallel shfls)
        float d1 = __shfl(dotv, 16);
        float d2 = __shfl(dotv, 32);
        float d3 = __shfl(dotv, 48);

        if (owner) {
            float iv = sigmoidf_(xi  + dotv);
            float fv = sigmoidf_(xf  + d1);
            float gv = tanhf_   (xgg + d2);
            float ov = sigmoidf_(xo  + d3);
            c_state = fv * c_state + iv * gv;
            h_state = ov * tanhf_(c_state);
            // direct register publish, no extra barrier:
            // (1) sc0 store -> shared XCD L2 (fast path for colocated readers)
            // (2) agent store -> MALL (fallback-path correctness)
            unsigned val = __float_as_uint(h_state);
            unsigned* dst = (unsigned*)(g_hp + (size_t)(np + 1) * HROW
                                        + b * HSLOT) + u;
            asm volatile("global_store_dword %0, %1, off sc0"
                         :: "v"(dst), "v"(val) : "memory");
            __hip_atomic_store(dst, val, __ATOMIC_RELAXED,
                               __HIP_MEMORY_SCOPE_AGENT);
        }
        np++;
    }

    if (owner) {
        int uo = b * UPB + u;
        out[uo]              = any ? h_state : 0.f;  // out
        out[HIDDEN + uo]     = h_state;              // h_final
        out[2 * HIDDEN + uo] = c_state;              // c_final
    }
    if (b == 0 && tid == 0) {
        __hip_atomic_store(&g_done, 1u, __ATOMIC_RELAXED,
                           __HIP_MEMORY_SCOPE_AGENT);
    }
}

// ---------------------------------------------------------------------------
extern "C" void kernel_launch(void* const* d_in, const int* in_sizes, int n_in,
                              void* d_out, int out_size, void* d_ws, size_t ws_size,
                              hipStream_t stream)
{
    const int*   seq  = (const int*)  d_in[0];
    const float* h0   = (const float*)d_in[1];
    const float* c0   = (const float*)d_in[2];
    const float* emb  = (const float*)d_in[3];
    const float* W_ih = (const float*)d_in[4];
    const float* W_hh = (const float*)d_in[5];
    const float* b_ih = (const float*)d_in[6];
    const float* b_hh = (const float*)d_in[7];
    float* out = (float*)d_out;

    hipLaunchKernelGGL(xgates_kernel, dim3(256), dim3(256), 0, stream,
                       seq, h0, emb, W_ih, b_ih, b_hh);

    void* args[] = { (void*)&seq, (void*)&h0, (void*)&c0, (void*)&W_hh,
                     (void*)&out };
    hipLaunchCooperativeKernel((const void*)lstm_kernel, dim3(NBLK), dim3(TPB),
                               args, 0, stream);
}

// Round 8
// 2361.645 us; speedup vs baseline: 6.0237x; 6.0237x over previous
//
#include <hip/hip_runtime.h>
#include <math.h>

#define SEQ    1024
#define EMBED  300
#define HIDDEN 512
#define G4     2048          // 4*HIDDEN, gate order i,f,g,o
#define NB     128           // worker blocks in phase 2
#define NBLK   256           // total blocks (128 workers + 128 heaters)
#define TPB    256           // threads per block (4 waves)
#define UPB    (HIDDEN/NB)   // hidden units owned per worker block = 4
#define PAD_IDX 1
#define SENT   0x7FC00BADu   // NaN bit pattern: never produced by LSTM math

// g_hp layout: [step][producer][32 floats] -- 128 B per producer per step:
// each producer owns its cache line exclusively (no hot-line sharing; R3's
// 128-block contention came from 16 unpadded lines @ 2048 hits/line).
#define HSLOT  32
#define HROW   (NB * HSLOT)   // 4096 floats per step

// ---- device-global scratch. Fully re-initialized by phase 1 every call. ----
__device__ float        g_xg[SEQ * G4];            // x @ W_ih^T + b_ih + b_hh
__device__ float        g_hp[(SEQ + 1) * HROW];    // padded per-step h buffers
__device__ unsigned int g_done;                    // heater kill switch
__device__ float        g_sink;                    // keeps heater loops alive

__device__ __forceinline__ float sigmoidf_(float x) {
    return 1.f / (1.f + __expf(-x));
}
// saturating fast tanh: 1 - 2/(e^2x + 1)
__device__ __forceinline__ float tanhf_(float x) {
    return 1.f - 2.f / (__expf(2.f * x) + 1.f);
}

// DPP butterfly add over 16-lane rows (xor 1,2,7,15)
#define DPP_ADD(v, ctrl)                                                      \
    (v) += __int_as_float(__builtin_amdgcn_update_dpp(                        \
        0, __float_as_int(v), (ctrl), 0xf, 0xf, true))

// ---------------------------------------------------------------------------
// Phase 1: xg[t][k] = dot(emb[token[t]], W_ih[k]) + b_ih[k] + b_hh[k]
// grid = 256 blocks (128 t-tiles of 8 tokens x 2 k-halves), 256 threads.
// Also: g_hp step 0 = h0, steps 1..SEQ = sentinel; g_done = 0.
// ---------------------------------------------------------------------------
__global__ __launch_bounds__(256) void xgates_kernel(
    const int* __restrict__ seq, const float* __restrict__ h0,
    const float* __restrict__ emb, const float* __restrict__ W_ih,
    const float* __restrict__ b_ih, const float* __restrict__ b_hh)
{
    const int bx = blockIdx.x, tid = threadIdx.x;

    if (bx == 0 && tid == 0) g_done = 0u;
    // (SEQ+1)*HROW = 4.2M floats, grid-strided over 65536 threads
    for (int i = bx * 256 + tid; i < (SEQ + 1) * HROW; i += 256 * 256) {
        int step = i >> 12, slot = i & (HROW - 1);
        int blk = slot >> 5, k = slot & (HSLOT - 1);
        float v = __uint_as_float(SENT);
        if (step == 0 && k < UPB) v = h0[blk * UPB + k];
        g_hp[i] = v;
    }

    const int t_tile = bx >> 1, k_half = bx & 1;
    const int t0 = t_tile * 8;

    __shared__ int tok_s[8];
    __shared__ __align__(16) float embt[8][304];

    if (tid < 8) tok_s[tid] = seq[t0 + tid];
    __syncthreads();
    for (int idx = tid; idx < 8 * EMBED; idx += 256) {
        int tt = idx / EMBED;
        int e  = idx - tt * EMBED;
        embt[tt][e] = emb[(size_t)tok_s[tt] * EMBED + e];
    }
    __syncthreads();

    const int kbase = k_half * 1024 + tid;
    const float4* wr0 = (const float4*)(W_ih + (size_t)(kbase      ) * EMBED);
    const float4* wr1 = (const float4*)(W_ih + (size_t)(kbase + 256) * EMBED);
    const float4* wr2 = (const float4*)(W_ih + (size_t)(kbase + 512) * EMBED);
    const float4* wr3 = (const float4*)(W_ih + (size_t)(kbase + 768) * EMBED);

    float acc[4][8];
    #pragma unroll
    for (int kk = 0; kk < 4; kk++)
        #pragma unroll
        for (int tt = 0; tt < 8; tt++) acc[kk][tt] = 0.f;

    for (int e4 = 0; e4 < EMBED / 4; e4++) {  // 75 iters
        float4 em[8];
        #pragma unroll
        for (int tt = 0; tt < 8; tt++)
            em[tt] = *(const float4*)&embt[tt][e4 * 4];
        float4 w[4];
        w[0] = wr0[e4]; w[1] = wr1[e4]; w[2] = wr2[e4]; w[3] = wr3[e4];
        #pragma unroll
        for (int kk = 0; kk < 4; kk++) {
            #pragma unroll
            for (int tt = 0; tt < 8; tt++) {
                float a = acc[kk][tt];
                a = fmaf(w[kk].x, em[tt].x, a);
                a = fmaf(w[kk].y, em[tt].y, a);
                a = fmaf(w[kk].z, em[tt].z, a);
                a = fmaf(w[kk].w, em[tt].w, a);
                acc[kk][tt] = a;
            }
        }
    }
    #pragma unroll
    for (int kk = 0; kk < 4; kk++) {
        int k = kbase + kk * 256;
        float bias = b_ih[k] + b_hh[k];
        #pragma unroll
        for (int tt = 0; tt < 8; tt++)
            g_xg[(size_t)(t0 + tt) * G4 + k] = acc[kk][tt] + bias;
    }
}

// ---------------------------------------------------------------------------
// Phase 2: persistent cooperative LSTM (data-as-signal, agent-scope -- the
// R6-proven exchange) spread over 128 worker CUs + 128 heater blocks.
//
// Why 128 workers: R6's 32-block shape pushed 131 KB/step of ds_read_b128
// through ONE CU's LDS pipe (~1540 cy/step, the dominant serial term).
// 16 rows/block -> 32 KB/step/CU (~376 cy). Rows: wave u owns unit b*4+u,
// lane = g*16+c; 8 float4 of W_hh per thread (VGPR-resident, R3-proven).
//
// Poll: all 256 threads, ONE 8-B piece each (producer blk=tid>>1, j=tid&1),
// 4-deep pipelined batch (4 independent atomic loads in flight: detection
// phase error ~0.6 RTT vs 1.0 RTT for a dependent spin). Value never
// transitions twice, so any non-sentinel copy is THE value.
//
// Heaters: blocks 128..255, 128 threads of register FMA (R5-proven SCLK
// boost; lighter than R6 to stay off the power cap).
// ---------------------------------------------------------------------------
__global__ __launch_bounds__(TPB, 1) void lstm_kernel(
    const int* __restrict__ seq, const float* __restrict__ h0,
    const float* __restrict__ c0, const float* __restrict__ Whh,
    float* __restrict__ out)
{
    const int b = blockIdx.x, tid = threadIdx.x;

    if (b >= NB) {
        // ---------------- heater ----------------
        if (tid < 128) {
            float a0 = 1.0f + tid, a1 = 2.0f, a2 = 3.0f, a3 = 4.0f;
            for (;;) {
                #pragma unroll
                for (int i = 0; i < 128; i++) {
                    a0 = fmaf(a0, 1.000001f, 0.5f);
                    a1 = fmaf(a1, 0.999999f, 0.25f);
                    a2 = fmaf(a2, 1.0000005f, a0);
                    a3 = fmaf(a3, 0.9999995f, a1);
                }
                if (__hip_atomic_load(&g_done, __ATOMIC_RELAXED,
                                      __HIP_MEMORY_SCOPE_AGENT)) break;
            }
            if (a0 == 1234.5678f && a1 == a2) g_sink = a3;
        }
        return;
    }

    // ---------------- worker ----------------
    const int u = tid >> 6;            // wave id = owned unit 0..3
    const int lane = tid & 63;
    const int g = lane >> 4, c = lane & 15;
    const int R = g * HIDDEN + b * UPB + u;    // W_hh row

    const float* wrow = Whh + (size_t)R * HIDDEN + c * 32;
    float4 wreg[8];
    #pragma unroll
    for (int i = 0; i < 8; i++) {
        int off = (4 * i + 4 * c) & 31;   // rotated traversal (bank spread)
        wreg[i] = *(const float4*)(wrow + off);
    }

    __shared__ __align__(16) float h_lds[2][HIDDEN];
    __shared__ int tok_lds[SEQ];

    for (int i = tid; i < SEQ; i += TPB) tok_lds[i] = seq[i];

    const bool owner = (lane == 0);
    float c_state = 0.f, h_state = 0.f;
    if (owner) {
        c_state = c0[b * UPB + u];
        h_state = h0[b * UPB + u];
    }
    __syncthreads();   // tok_lds ready

    int np = 0;
    bool any = false;

    for (int t = 0; t < SEQ; t++) {
        int tok = tok_lds[t];             // uniform LDS read
        if (tok == PAD_IDX) continue;     // uniform across grid
        any = true;

        // owner xg loads issued FIRST: independent, in flight under the poll
        float xi = 0.f, xf = 0.f, xgg = 0.f, xo = 0.f;
        if (owner) {
            const float* xr = g_xg + (size_t)t * G4 + b * UPB + u;
            xi  = xr[0];
            xf  = xr[HIDDEN];
            xgg = xr[2 * HIDDEN];
            xo  = xr[3 * HIDDEN];
        }

        // ALL 256 threads: one 8-B piece (producer blk = tid>>1, j = tid&1),
        // 4-deep pipelined poll. Any non-sentinel copy is the final value.
        {
            const int blk = tid >> 1, j = tid & 1;
            const unsigned long long* hb = (const unsigned long long*)
                (g_hp + (size_t)np * HROW + blk * HSLOT) + j;
            unsigned long long v;
            for (;;) {
                unsigned long long p0 = __hip_atomic_load(hb, __ATOMIC_RELAXED,
                                            __HIP_MEMORY_SCOPE_AGENT);
                unsigned long long p1 = __hip_atomic_load(hb, __ATOMIC_RELAXED,
                                            __HIP_MEMORY_SCOPE_AGENT);
                unsigned long long p2 = __hip_atomic_load(hb, __ATOMIC_RELAXED,
                                            __HIP_MEMORY_SCOPE_AGENT);
                unsigned long long p3 = __hip_atomic_load(hb, __ATOMIC_RELAXED,
                                            __HIP_MEMORY_SCOPE_AGENT);
                if ((unsigned)p0 != SENT && (unsigned)(p0 >> 32) != SENT) { v = p0; break; }
                if ((unsigned)p1 != SENT && (unsigned)(p1 >> 32) != SENT) { v = p1; break; }
                if ((unsigned)p2 != SENT && (unsigned)(p2 >> 32) != SENT) { v = p2; break; }
                if ((unsigned)p3 != SENT && (unsigned)(p3 >> 32) != SENT) { v = p3; break; }
            }
            *(unsigned long long*)&h_lds[np & 1][blk * UPB + 2 * j] = v;
        }
        __syncthreads();   // the only barrier per step

        // 32-length partial dot: W from VGPRs, h via LDS broadcasts
        const float* hc = h_lds[np & 1] + c * 32;
        float4 a4 = {0.f, 0.f, 0.f, 0.f};
        #pragma unroll
        for (int i = 0; i < 8; i++) {
            int off = (4 * i + 4 * c) & 31;
            float4 h4 = *(const float4*)(hc + off);
            a4.x = fmaf(wreg[i].x, h4.x, a4.x);
            a4.y = fmaf(wreg[i].y, h4.y, a4.y);
            a4.z = fmaf(wreg[i].z, h4.z, a4.z);
            a4.w = fmaf(wreg[i].w, h4.w, a4.w);
        }
        float dotv = (a4.x + a4.y) + (a4.z + a4.w);
        // 16-lane butterfly via DPP (xor1, xor2, xor7, xor15): pure VALU
        DPP_ADD(dotv, 0xB1);    // quad_perm [1,0,3,2]
        DPP_ADD(dotv, 0x4E);    // quad_perm [2,3,0,1]
        DPP_ADD(dotv, 0x141);   // row_half_mirror
        DPP_ADD(dotv, 0x140);   // row_mirror

        // owner (lane 0) holds d0; gather d1..d3 (3 parallel shfls)
        float d1 = __shfl(dotv, 16);
        float d2 = __shfl(dotv, 32);
        float d3 = __shfl(dotv, 48);

        if (owner) {
            float iv = sigmoidf_(xi  + dotv);
            float fv = sigmoidf_(xf  + d1);
            float gv = tanhf_   (xgg + d2);
            float ov = sigmoidf_(xo  + d3);
            c_state = fv * c_state + iv * gv;
            h_state = ov * tanhf_(c_state);
            // direct register publish into this block's exclusive line
            __hip_atomic_store(
                (unsigned*)(g_hp + (size_t)(np + 1) * HROW + b * HSLOT) + u,
                __float_as_uint(h_state),
                __ATOMIC_RELAXED, __HIP_MEMORY_SCOPE_AGENT);
        }
        np++;
    }

    if (owner) {
        int uo = b * UPB + u;
        out[uo]              = any ? h_state : 0.f;  // out
        out[HIDDEN + uo]     = h_state;              // h_final
        out[2 * HIDDEN + uo] = c_state;              // c_final
    }
    if (b == 0 && tid == 0) {
        __hip_atomic_store(&g_done, 1u, __ATOMIC_RELAXED,
                           __HIP_MEMORY_SCOPE_AGENT);
    }
}

// ---------------------------------------------------------------------------
extern "C" void kernel_launch(void* const* d_in, const int* in_sizes, int n_in,
                              void* d_out, int out_size, void* d_ws, size_t ws_size,
                              hipStream_t stream)
{
    const int*   seq  = (const int*)  d_in[0];
    const float* h0   = (const float*)d_in[1];
    const float* c0   = (const float*)d_in[2];
    const float* emb  = (const float*)d_in[3];
    const float* W_ih = (const float*)d_in[4];
    const float* W_hh = (const float*)d_in[5];
    const float* b_ih = (const float*)d_in[6];
    const float* b_hh = (const float*)d_in[7];
    float* out = (float*)d_out;

    hipLaunchKernelGGL(xgates_kernel, dim3(256), dim3(256), 0, stream,
                       seq, h0, emb, W_ih, b_ih, b_hh);

    void* args[] = { (void*)&seq, (void*)&h0, (void*)&c0, (void*)&W_hh,
                     (void*)&out };
    hipLaunchCooperativeKernel((const void*)lstm_kernel, dim3(NBLK), dim3(TPB),
                               args, 0, stream);
}

// Round 9
// 1836.234 us; speedup vs baseline: 7.7473x; 1.2861x over previous
//
#include <hip/hip_runtime.h>
#include <math.h>

#define SEQ    1024
#define EMBED  300
#define HIDDEN 512
#define G4     2048          // 4*HIDDEN, gate order i,f,g,o
#define NB     128           // worker blocks in phase 2
#define NBLK   256           // total blocks (128 workers + 128 heaters)
#define TPB    256           // threads per block (4 waves)
#define UPB    (HIDDEN/NB)   // hidden units owned per worker block = 4
#define PAD_IDX 1
#define SENT   0x7FC00BADu   // NaN bit pattern: never produced by LSTM math

// g_hp layout: [step][producer][32 floats] -- 128 B per producer per step:
// each producer owns its cache line exclusively. Real payload = first 16 B.
#define HSLOT  32
#define HROW   (NB * HSLOT)   // 4096 floats per step

// ---- device-global scratch. Fully re-initialized by phase 1 every call. ----
__device__ float        g_xg[SEQ * G4];            // x @ W_ih^T + b_ih + b_hh
__device__ float        g_hp[(SEQ + 1) * HROW];    // padded per-step h buffers
__device__ unsigned int g_done;                    // heater kill switch
__device__ float        g_sink;                    // keeps heater loops alive

__device__ __forceinline__ float sigmoidf_(float x) {
    return 1.f / (1.f + __expf(-x));
}
// saturating fast tanh: 1 - 2/(e^2x + 1)
__device__ __forceinline__ float tanhf_(float x) {
    return 1.f - 2.f / (__expf(2.f * x) + 1.f);
}

// DPP butterfly add over 16-lane rows (xor 1,2,7,15)
#define DPP_ADD(v, ctrl)                                                      \
    (v) += __int_as_float(__builtin_amdgcn_update_dpp(                        \
        0, __float_as_int(v), (ctrl), 0xf, 0xf, true))

// ---------------------------------------------------------------------------
// Phase 1: xg[t][k] = dot(emb[token[t]], W_ih[k]) + b_ih[k] + b_hh[k]
// grid = 256 blocks (128 t-tiles of 8 tokens x 2 k-halves), 256 threads.
// Also: g_hp step 0 = h0, steps 1..SEQ = sentinel; g_done = 0.
// ---------------------------------------------------------------------------
__global__ __launch_bounds__(256) void xgates_kernel(
    const int* __restrict__ seq, const float* __restrict__ h0,
    const float* __restrict__ emb, const float* __restrict__ W_ih,
    const float* __restrict__ b_ih, const float* __restrict__ b_hh)
{
    const int bx = blockIdx.x, tid = threadIdx.x;

    if (bx == 0 && tid == 0) g_done = 0u;
    for (int i = bx * 256 + tid; i < (SEQ + 1) * HROW; i += 256 * 256) {
        int step = i >> 12, slot = i & (HROW - 1);
        int blk = slot >> 5, k = slot & (HSLOT - 1);
        float v = __uint_as_float(SENT);
        if (step == 0 && k < UPB) v = h0[blk * UPB + k];
        g_hp[i] = v;
    }

    const int t_tile = bx >> 1, k_half = bx & 1;
    const int t0 = t_tile * 8;

    __shared__ int tok_s[8];
    __shared__ __align__(16) float embt[8][304];

    if (tid < 8) tok_s[tid] = seq[t0 + tid];
    __syncthreads();
    for (int idx = tid; idx < 8 * EMBED; idx += 256) {
        int tt = idx / EMBED;
        int e  = idx - tt * EMBED;
        embt[tt][e] = emb[(size_t)tok_s[tt] * EMBED + e];
    }
    __syncthreads();

    const int kbase = k_half * 1024 + tid;
    const float4* wr0 = (const float4*)(W_ih + (size_t)(kbase      ) * EMBED);
    const float4* wr1 = (const float4*)(W_ih + (size_t)(kbase + 256) * EMBED);
    const float4* wr2 = (const float4*)(W_ih + (size_t)(kbase + 512) * EMBED);
    const float4* wr3 = (const float4*)(W_ih + (size_t)(kbase + 768) * EMBED);

    float acc[4][8];
    #pragma unroll
    for (int kk = 0; kk < 4; kk++)
        #pragma unroll
        for (int tt = 0; tt < 8; tt++) acc[kk][tt] = 0.f;

    for (int e4 = 0; e4 < EMBED / 4; e4++) {  // 75 iters
        float4 em[8];
        #pragma unroll
        for (int tt = 0; tt < 8; tt++)
            em[tt] = *(const float4*)&embt[tt][e4 * 4];
        float4 w[4];
        w[0] = wr0[e4]; w[1] = wr1[e4]; w[2] = wr2[e4]; w[3] = wr3[e4];
        #pragma unroll
        for (int kk = 0; kk < 4; kk++) {
            #pragma unroll
            for (int tt = 0; tt < 8; tt++) {
                float a = acc[kk][tt];
                a = fmaf(w[kk].x, em[tt].x, a);
                a = fmaf(w[kk].y, em[tt].y, a);
                a = fmaf(w[kk].z, em[tt].z, a);
                a = fmaf(w[kk].w, em[tt].w, a);
                acc[kk][tt] = a;
            }
        }
    }
    #pragma unroll
    for (int kk = 0; kk < 4; kk++) {
        int k = kbase + kk * 256;
        float bias = b_ih[k] + b_hh[k];
        #pragma unroll
        for (int tt = 0; tt < 8; tt++)
            g_xg[(size_t)(t0 + tt) * G4 + k] = acc[kk][tt] + bias;
    }
}

// ---------------------------------------------------------------------------
// Phase 2: persistent cooperative LSTM (data-as-signal, agent-scope, the
// R6/R8-proven exchange), critical-path-trimmed.
//
// 128 workers x 256 threads + 128 FMA heater blocks. Wave u owns unit
// b*4+u; lane = g*16+c; 8 float4 of W_hh per thread (VGPR-resident).
//
// R9 trims (targeting the ~2300cy serial step at the ~1.1 GHz effective
// clock calibrated from R7's retry data):
//  - poll: 128 pollers, ONE dependent 16-B probe each (two independent 8-B
//    atomic loads, single waitcnt) -- 4x fewer in-flight MALL requests than
//    R8's 256x4-deep, detection still ~1 RTT.
//  - distributed activations: lanes {0,16,32,48} compute their own gate's
//    sigmoid/tanh BEFORE the cross-lane gather (removes ~3 serialized exp
//    latencies from the owner tail). Gate-lane xg loads issued pre-poll.
//  - owner tail: c/h update + 1 tanh + immediate publish only.
// ---------------------------------------------------------------------------
__global__ __launch_bounds__(TPB, 1) void lstm_kernel(
    const int* __restrict__ seq, const float* __restrict__ h0,
    const float* __restrict__ c0, const float* __restrict__ Whh,
    float* __restrict__ out)
{
    const int b = blockIdx.x, tid = threadIdx.x;

    if (b >= NB) {
        // ---------------- heater ----------------
        if (tid < 128) {
            float a0 = 1.0f + tid, a1 = 2.0f, a2 = 3.0f, a3 = 4.0f;
            for (;;) {
                #pragma unroll
                for (int i = 0; i < 128; i++) {
                    a0 = fmaf(a0, 1.000001f, 0.5f);
                    a1 = fmaf(a1, 0.999999f, 0.25f);
                    a2 = fmaf(a2, 1.0000005f, a0);
                    a3 = fmaf(a3, 0.9999995f, a1);
                }
                if (__hip_atomic_load(&g_done, __ATOMIC_RELAXED,
                                      __HIP_MEMORY_SCOPE_AGENT)) break;
            }
            if (a0 == 1234.5678f && a1 == a2) g_sink = a3;
        }
        return;
    }

    // ---------------- worker ----------------
    const int u = tid >> 6;            // wave id = owned unit 0..3
    const int lane = tid & 63;
    const int g = lane >> 4, c = lane & 15;
    const int R = g * HIDDEN + b * UPB + u;    // W_hh row

    const float* wrow = Whh + (size_t)R * HIDDEN + c * 32;
    float4 wreg[8];
    #pragma unroll
    for (int i = 0; i < 8; i++) {
        int off = (4 * i + 4 * c) & 31;   // rotated traversal (bank spread)
        wreg[i] = *(const float4*)(wrow + off);
    }

    __shared__ __align__(16) float h_lds[2][HIDDEN];
    __shared__ int tok_lds[SEQ];

    for (int i = tid; i < SEQ; i += TPB) tok_lds[i] = seq[i];

    const bool owner = (lane == 0);
    const bool gate_lane = (c == 0);     // lanes 0,16,32,48 of each wave
    float c_state = 0.f, h_state = 0.f;
    if (owner) {
        c_state = c0[b * UPB + u];
        h_state = h0[b * UPB + u];
    }
    __syncthreads();   // tok_lds ready

    int np = 0;
    bool any = false;

    for (int t = 0; t < SEQ; t++) {
        int tok = tok_lds[t];             // uniform LDS read
        if (tok == PAD_IDX) continue;     // uniform across grid
        any = true;

        // gate-lane xg loads issued FIRST: in flight under the poll
        float xgv = 0.f;
        if (gate_lane) {
            xgv = g_xg[(size_t)t * G4 + g * HIDDEN + b * UPB + u];
        }

        // 128 pollers: ONE dependent 16-B probe (two independent 8-B atomic
        // loads, one waitcnt). Piece = producer tid's 4 units. Each 4B word
        // transitions once; partial views just retry.
        if (tid < NB) {
            const unsigned long long* hb = (const unsigned long long*)
                (g_hp + (size_t)np * HROW + tid * HSLOT);
            unsigned long long p0, p1;
            for (;;) {
                p0 = __hip_atomic_load(hb + 0, __ATOMIC_RELAXED,
                                       __HIP_MEMORY_SCOPE_AGENT);
                p1 = __hip_atomic_load(hb + 1, __ATOMIC_RELAXED,
                                       __HIP_MEMORY_SCOPE_AGENT);
                if ((unsigned)p0 != SENT && (unsigned)(p0 >> 32) != SENT &&
                    (unsigned)p1 != SENT && (unsigned)(p1 >> 32) != SENT)
                    break;
            }
            unsigned long long* dst =
                (unsigned long long*)&h_lds[np & 1][tid * UPB];
            dst[0] = p0; dst[1] = p1;
        }
        __syncthreads();   // the only barrier per step

        // 32-length partial dot: W from VGPRs, h via LDS broadcasts
        const float* hc = h_lds[np & 1] + c * 32;
        float4 a4 = {0.f, 0.f, 0.f, 0.f};
        #pragma unroll
        for (int i = 0; i < 8; i++) {
            int off = (4 * i + 4 * c) & 31;
            float4 h4 = *(const float4*)(hc + off);
            a4.x = fmaf(wreg[i].x, h4.x, a4.x);
            a4.y = fmaf(wreg[i].y, h4.y, a4.y);
            a4.z = fmaf(wreg[i].z, h4.z, a4.z);
            a4.w = fmaf(wreg[i].w, h4.w, a4.w);
        }
        float dotv = (a4.x + a4.y) + (a4.z + a4.w);
        // 16-lane butterfly via DPP (xor1, xor2, xor7, xor15): pure VALU
        DPP_ADD(dotv, 0xB1);    // quad_perm [1,0,3,2]
        DPP_ADD(dotv, 0x4E);    // quad_perm [2,3,0,1]
        DPP_ADD(dotv, 0x141);   // row_half_mirror
        DPP_ADD(dotv, 0x140);   // row_mirror

        // distributed activations: each gate lane applies its nonlinearity
        float act = 0.f;
        if (gate_lane) {
            float z = xgv + dotv;
            act = (g == 2) ? tanhf_(z) : sigmoidf_(z);
        }
        // owner gathers ACTIVATED gate values (3 parallel shfls)
        float fv = __shfl(act, 16);
        float gv = __shfl(act, 32);
        float ov = __shfl(act, 48);

        if (owner) {
            c_state = fv * c_state + act * gv;   // act == iv on lane 0
            h_state = ov * tanhf_(c_state);
            // direct register publish into this block's exclusive line
            __hip_atomic_store(
                (unsigned*)(g_hp + (size_t)(np + 1) * HROW + b * HSLOT) + u,
                __float_as_uint(h_state),
                __ATOMIC_RELAXED, __HIP_MEMORY_SCOPE_AGENT);
        }
        np++;
    }

    if (owner) {
        int uo = b * UPB + u;
        out[uo]              = any ? h_state : 0.f;  // out
        out[HIDDEN + uo]     = h_state;              // h_final
        out[2 * HIDDEN + uo] = c_state;              // c_final
    }
    if (b == 0 && tid == 0) {
        __hip_atomic_store(&g_done, 1u, __ATOMIC_RELAXED,
                           __HIP_MEMORY_SCOPE_AGENT);
    }
}

// ---------------------------------------------------------------------------
extern "C" void kernel_launch(void* const* d_in, const int* in_sizes, int n_in,
                              void* d_out, int out_size, void* d_ws, size_t ws_size,
                              hipStream_t stream)
{
    const int*   seq  = (const int*)  d_in[0];
    const float* h0   = (const float*)d_in[1];
    const float* c0   = (const float*)d_in[2];
    const float* emb  = (const float*)d_in[3];
    const float* W_ih = (const float*)d_in[4];
    const float* W_hh = (const float*)d_in[5];
    const float* b_ih = (const float*)d_in[6];
    const float* b_hh = (const float*)d_in[7];
    float* out = (float*)d_out;

    hipLaunchKernelGGL(xgates_kernel, dim3(256), dim3(256), 0, stream,
                       seq, h0, emb, W_ih, b_ih, b_hh);

    void* args[] = { (void*)&seq, (void*)&h0, (void*)&c0, (void*)&W_hh,
                     (void*)&out };
    hipLaunchCooperativeKernel((const void*)lstm_kernel, dim3(NBLK), dim3(TPB),
                               args, 0, stream);
}